// Round 6
// baseline (276.460 us; speedup 1.0000x reference)
//
#include <hip/hip_runtime.h>
#include <math.h>

#define HOP     128
#define NSLOTS  256
#define FPW     4      // frames per chain; 1 chain per 64-thread block -> 8192 blocks
#define PI_F    3.14159265358979323846f
#define PI2_F   1.57079632679489661923f
#define K8      0.70710678118654752440f

// Zero-instruction ordering fence for intra-wave LDS cross-lane handoffs.
#define LDS_FENCE() do { __asm__ volatile("" ::: "memory"); \
                         __builtin_amdgcn_wave_barrier(); } while (0)

struct cpx { float x, y; };
__device__ __forceinline__ cpx cadd(cpx a, cpx b){ return {a.x+b.x, a.y+b.y}; }
__device__ __forceinline__ cpx csub(cpx a, cpx b){ return {a.x-b.x, a.y-b.y}; }
__device__ __forceinline__ cpx cmul(cpx a, cpx b){
    return {fmaf(a.x,b.x,-a.y*b.y), fmaf(a.x,b.y, a.y*b.x)};
}
__device__ __forceinline__ cpx cmulc(cpx a, cpx b){  // a*conj(b)
    return {fmaf(a.x,b.x, a.y*b.y), fmaf(a.y,b.x,-a.x*b.y)};
}

// |atan2(im,re)| in [0,pi]
__device__ __forceinline__ float abs_angle(float re, float im) {
    float a = fabsf(im), b = fabsf(re);
    float mn = fminf(a, b), mx = fmaxf(a, b);
    float t = __fdividef(mn, fmaxf(mx, 1e-37f));
    float t2 = t * t;
    float p = fmaf(t2, -0.0117212f, 0.05265332f);
    p = fmaf(t2, p, -0.11643287f);
    p = fmaf(t2, p, 0.19354346f);
    p = fmaf(t2, p, -0.33262347f);
    p = fmaf(t2, p, 0.99997726f);
    float r = t * p;
    r = (a > b) ? (PI2_F - r) : r;
    r = (re < 0.f) ? (PI_F - r) : r;
    return r;
}

// In-register 8-point DFT, natural-order output.
__device__ __forceinline__ void dft8(cpx v[8]) {
    cpx a0=cadd(v[0],v[4]), a1=cadd(v[1],v[5]), a2=cadd(v[2],v[6]), a3=cadd(v[3],v[7]);
    cpx b0=csub(v[0],v[4]), b1=csub(v[1],v[5]), b2=csub(v[2],v[6]), b3=csub(v[3],v[7]);
    b1 = cpx{K8*(b1.x+b1.y), K8*(b1.y-b1.x)};   // * e^{-i pi/4}
    b2 = cpx{b2.y, -b2.x};                      // * -i
    b3 = cpx{K8*(b3.y-b3.x), -K8*(b3.x+b3.y)};  // * e^{-3i pi/4}
    cpx c0=cadd(a0,a2), c2=csub(a0,a2);
    cpx c1=cadd(a1,a3), c3=csub(a1,a3); c3 = cpx{c3.y, -c3.x};
    cpx d0=cadd(b0,b2), d2=csub(b0,b2);
    cpx d1=cadd(b1,b3), d3=csub(b1,b3); d3 = cpx{d3.y, -d3.x};
    v[0]=cadd(c0,c1); v[4]=csub(c0,c1);
    v[2]=cadd(c2,c3); v[6]=csub(c2,c3);
    v[1]=cadd(d0,d1); v[5]=csub(d0,d1);
    v[3]=cadd(d2,d3); v[7]=csub(d2,d3);
}

// 1-wave blocks: the residency quantum is a single wave + 4.6KB LDS, so the
// HW scheduler fills wave slots directly (32/CU) and blocks retire
// independently — no 4-wave barrier coupling, no 17KB LDS granularity.
// Register budget lesson (r1-r3): tw1 in VGPRs (14), tw2 in LDS broadcast,
// Hermitian partner via shuffle. Peak live ~58 < 64.
__global__ __launch_bounds__(64, 4) void phase_loss_kernel(
        const float* __restrict__ y, const float* __restrict__ g,
        float* __restrict__ acc, int* __restrict__ ticket,
        float* __restrict__ out, int T, int n_frames, float inv_count) {
    __shared__ float2 xch[512];      // XOR-swizzled transpose scratch (one wave)
    __shared__ float2 tw2_tab[7][8]; // W64^{(lane&7)*k}, k=1..7 (broadcast reads)
    __shared__ int is_last;

    const int lane = threadIdx.x;    // 0..63
    const int l8   = lane & 7;

    // tw2 table once per block (same __sincosf expressions -> bit-identical).
    if (lane < 56) {
        const int k = (lane >> 3) + 1, l = lane & 7;
        float s, c;
        __sincosf(-(2.0f * PI_F / 64.0f) * (float)(l * k), &s, &c);
        tw2_tab[lane >> 3][l] = make_float2(c, s);
    }
    LDS_FENCE();   // single wave: ordering fence suffices, no s_barrier needed

    // Stage-1 twiddles in registers (14 VGPRs), once per kernel.
    cpx tw1[7];
    #pragma unroll
    for (int k = 1; k < 8; ++k) {
        float a1 = -(2.0f * PI_F / 512.0f) * (float)(lane * k);
        __sincosf(a1, &tw1[k - 1].y, &tw1[k - 1].x);
    }

    float ip = 0.f, gd = 0.f, iaf = 0.f;
    cpx Cp[5];
    const int tmax_int = (T - 256) / HOP;   // frames [2, tmax_int] need no reflect
    const int ra1 = (lane >> 3) * 72 + (lane & 7);       // stage-1 read base, XOR (r<<3)
    const int ra2 = (lane >> 3) * 65 + (lane & 7) * 8;   // stage-2 read base, XOR r
    const int rsl = (lane + 63) & 63;                    // rotate-down-1 shuffle source
    const int rsh = (64 - lane) & 63;                    // Hermitian partner source lane

    auto do_frame = [&](int t, bool accum, bool hp) {
        cpx v[8];
        const int base = t * HOP - 256 + lane;
        if (t >= 2 && t <= tmax_int) {       // fast path: no reflect clamps
            #pragma unroll
            for (int r = 0; r < 8; ++r) {
                int j = base + r * 64;
                v[r].x = y[j]; v[r].y = g[j];
            }
        } else {
            #pragma unroll
            for (int r = 0; r < 8; ++r) {
                int j = base + r * 64;
                j = (j < 0) ? -j : j;
                j = (j >= T) ? (2 * T - 2 - j) : j;
                v[r].x = y[j]; v[r].y = g[j];
            }
        }
        // stage 1: DFT8 over n2, twiddle W512^{lane*k} (registers)
        dft8(v);
        #pragma unroll
        for (int k = 1; k < 8; ++k) v[k] = cmul(v[k], tw1[k - 1]);
        LDS_FENCE();   // orders prev frame's stage-2 reads vs these writes
        #pragma unroll
        for (int k = 0; k < 8; ++k)
            xch[lane ^ (72 * k)] = make_float2(v[k].x, v[k].y);
        LDS_FENCE();
        #pragma unroll
        for (int r = 0; r < 8; ++r) {
            float2 tmp = xch[ra1 ^ (r << 3)];
            v[r] = cpx{tmp.x, tmp.y};
        }
        // stage 2: DFT8, twiddle W64^{(lane&7)*k} from LDS table (broadcast)
        dft8(v);
        #pragma unroll
        for (int k = 1; k < 8; ++k) {
            float2 tw = tw2_tab[k - 1][l8];
            v[k] = cmul(v[k], cpx{tw.x, tw.y});
        }
        LDS_FENCE();
        #pragma unroll
        for (int k = 0; k < 8; ++k)
            xch[lane ^ (65 * k)] = make_float2(v[k].x, v[k].y);
        LDS_FENCE();
        #pragma unroll
        for (int r = 0; r < 8; ++r) {
            float2 tmp = xch[ra2 ^ r];
            v[r] = cpx{tmp.x, tmp.y};
        }
        // stage 3: DFT8 -> bin f = lane + 64*reg, full spectrum in regs
        dft8(v);
        // Hermitian partner Z[(512-f)&511] via shuffle, no LDS round-trip:
        // lane>=1: partner = v[7-jj] from lane 64-lane; lane==0: own v[(8-jj)&7].
        cpx Cc[5];
        #pragma unroll
        for (int jj = 0; jj < 5; ++jj) {
            float px = __shfl(v[7 - jj].x, rsh, 64);
            float py = __shfl(v[7 - jj].y, rsh, 64);
            px = (lane == 0) ? v[(8 - jj) & 7].x : px;
            py = (lane == 0) ? v[(8 - jj) & 7].y : py;
            float ur = v[jj].x + px, ui = v[jj].y - py;   // 2*Y
            float vx = v[jj].x - px, vy = v[jj].y + py;   // 2i*G
            Cc[jj].x = fmaf(ur, vy, -ui * vx);            // C = Y*conj(G), x4
            Cc[jj].y = fmaf(ur, vx,  ui * vy);
        }
        if (accum) {
            // C[f-1] via lane-rotate shuffle; lane0 patched from previous jj.
            cpx rprev = {0.f, 0.f};
            #pragma unroll
            for (int jj = 0; jj < 4; ++jj) {
                cpx rj;
                rj.x = __shfl(Cc[jj].x, rsl, 64);
                rj.y = __shfl(Cc[jj].y, rsl, 64);
                cpx cmj = (jj > 0 && lane == 0) ? rprev : rj;
                cpx cc = Cc[jj];
                float aw = abs_angle(cc.x, cc.y);
                ip += aw;
                cpx qg = cmulc(cmj, cc);
                float gt = abs_angle(qg.x, qg.y);
                gd += (jj == 0 && lane == 0) ? aw : gt;   // gd row 0 term == ip term
                if (hp) {
                    cpx qi = cmulc(Cp[jj], cc);
                    iaf += abs_angle(qi.x, qi.y);
                } else {
                    iaf += aw;                             // iaf col 0 term == ip term
                }
                rprev = rj;
            }
            if (lane == 0) {   // bin 256
                cpx cc = Cc[4];
                float aw = abs_angle(cc.x, cc.y);
                ip += aw;
                cpx qg = cmulc(rprev, cc);                // rprev = C[255] at lane 0
                gd += abs_angle(qg.x, qg.y);
                if (hp) {
                    cpx qi = cmulc(Cp[4], cc);
                    iaf += abs_angle(qi.x, qi.y);
                } else {
                    iaf += aw;
                }
            }
        }
        #pragma unroll
        for (int jj = 0; jj < 5; ++jj) Cp[jj] = Cc[jj];
    };

    const int chain = (int)blockIdx.x;      // 1 chain per (1-wave) block
    const int t0 = chain * FPW;
    int tend = t0 + FPW;
    if (chain == (int)gridDim.x - 1) tend = n_frames;   // last chain takes remainder
    const bool havep = (t0 > 0);

    if (havep) do_frame(t0 - 1, false, false);
    #pragma unroll 2
    for (int t = t0; t < tend; ++t)
        do_frame(t, true, havep || (t > t0));

    // wave reduce
    for (int off = 32; off; off >>= 1) {
        ip  += __shfl_down(ip, off);
        gd  += __shfl_down(gd, off);
        iaf += __shfl_down(iaf, off);
    }
    if (lane == 0) {
        const int slot = (int)(blockIdx.x & (NSLOTS - 1));
        atomicAdd(acc + 0 * NSLOTS + slot, ip);
        atomicAdd(acc + 1 * NSLOTS + slot, gd);
        atomicAdd(acc + 2 * NSLOTS + slot, iaf);
        __threadfence();
        is_last = (atomicAdd(ticket, 1) == (int)gridDim.x - 1);
    }
    __syncthreads();
    if (is_last) {
        #pragma unroll
        for (int l = 0; l < 3; l++) {
            float vv = 0.f;
            #pragma unroll
            for (int k = 0; k < 4; ++k)
                vv += __hip_atomic_load(acc + l * NSLOTS + lane + (k << 6),
                                        __ATOMIC_RELAXED, __HIP_MEMORY_SCOPE_AGENT);
            for (int off = 32; off; off >>= 1) vv += __shfl_down(vv, off);
            if (lane == 0) out[l] = vv * inv_count;
        }
    }
}

extern "C" void kernel_launch(void* const* d_in, const int* in_sizes, int n_in,
                              void* d_out, int out_size, void* d_ws, size_t ws_size,
                              hipStream_t stream) {
    const float* y = (const float*)d_in[0];
    const float* g = (const float*)d_in[1];
    float* out = (float*)d_out;
    float* acc = (float*)d_ws;
    int* ticket = (int*)((char*)d_ws + 3 * NSLOTS * sizeof(float));
    const int T = in_sizes[0];
    const int n_frames = T / HOP + 1;                  // 32769
    int n_blocks = n_frames / FPW;                     // 8192 (last block absorbs rest)
    if (n_blocks < 1) n_blocks = 1;

    hipMemsetAsync(d_ws, 0, 3 * NSLOTS * sizeof(float) + sizeof(int), stream);
    const float inv_count = 1.0f / (257.0f * (float)n_frames);
    phase_loss_kernel<<<n_blocks, 64, 0, stream>>>(y, g, acc, ticket, out,
                                                   T, n_frames, inv_count);
}

// Round 7
// 135.977 us; speedup vs baseline: 2.0331x; 2.0331x over previous
//
#include <hip/hip_runtime.h>
#include <math.h>

#define HOP     128
#define NSLOTS  256
#define FPW     8      // frames per chain; 4096 chains / 1024 4-wave blocks
#define PI_F    3.14159265358979323846f
#define PI2_F   1.57079632679489661923f
#define K8      0.70710678118654752440f

// Zero-instruction ordering fence for intra-wave LDS cross-lane handoffs.
// Side effect we now exploit deliberately: the "memory" clobber pins global
// loads issued BEFORE it on that side — so prefetched loads stay hoisted.
#define LDS_FENCE() do { __asm__ volatile("" ::: "memory"); \
                         __builtin_amdgcn_wave_barrier(); } while (0)

struct cpx { float x, y; };
__device__ __forceinline__ cpx cadd(cpx a, cpx b){ return {a.x+b.x, a.y+b.y}; }
__device__ __forceinline__ cpx csub(cpx a, cpx b){ return {a.x-b.x, a.y-b.y}; }
__device__ __forceinline__ cpx cmul(cpx a, cpx b){
    return {fmaf(a.x,b.x,-a.y*b.y), fmaf(a.x,b.y, a.y*b.x)};
}
__device__ __forceinline__ cpx cmulc(cpx a, cpx b){  // a*conj(b)
    return {fmaf(a.x,b.x, a.y*b.y), fmaf(a.y,b.x,-a.x*b.y)};
}

// |atan2(im,re)| in [0,pi]
__device__ __forceinline__ float abs_angle(float re, float im) {
    float a = fabsf(im), b = fabsf(re);
    float mn = fminf(a, b), mx = fmaxf(a, b);
    float t = __fdividef(mn, fmaxf(mx, 1e-37f));
    float t2 = t * t;
    float p = fmaf(t2, -0.0117212f, 0.05265332f);
    p = fmaf(t2, p, -0.11643287f);
    p = fmaf(t2, p, 0.19354346f);
    p = fmaf(t2, p, -0.33262347f);
    p = fmaf(t2, p, 0.99997726f);
    float r = t * p;
    r = (a > b) ? (PI2_F - r) : r;
    r = (re < 0.f) ? (PI_F - r) : r;
    return r;
}

// In-register 8-point DFT, natural-order output.
__device__ __forceinline__ void dft8(cpx v[8]) {
    cpx a0=cadd(v[0],v[4]), a1=cadd(v[1],v[5]), a2=cadd(v[2],v[6]), a3=cadd(v[3],v[7]);
    cpx b0=csub(v[0],v[4]), b1=csub(v[1],v[5]), b2=csub(v[2],v[6]), b3=csub(v[3],v[7]);
    b1 = cpx{K8*(b1.x+b1.y), K8*(b1.y-b1.x)};   // * e^{-i pi/4}
    b2 = cpx{b2.y, -b2.x};                      // * -i
    b3 = cpx{K8*(b3.y-b3.x), -K8*(b3.x+b3.y)};  // * e^{-3i pi/4}
    cpx c0=cadd(a0,a2), c2=csub(a0,a2);
    cpx c1=cadd(a1,a3), c3=csub(a1,a3); c3 = cpx{c3.y, -c3.x};
    cpx d0=cadd(b0,b2), d2=csub(b0,b2);
    cpx d1=cadd(b1,b3), d3=csub(b1,b3); d3 = cpx{d3.y, -d3.x};
    v[0]=cadd(c0,c1); v[4]=csub(c0,c1);
    v[2]=cadd(c2,c3); v[6]=csub(c2,c3);
    v[1]=cadd(d0,d1); v[5]=csub(d0,d1);
    v[3]=cadd(d2,d3); v[7]=csub(d2,d3);
}

// 4-wave blocks (r6 lesson: sibling chains share L2 for frame overlaps).
// launch_bounds(256,2): prefetch adds ~16 live regs (peak ~78); give the
// allocator headroom rather than forcing 64 (r1 lesson: tight bound -> spill).
__global__ __launch_bounds__(256, 2) void phase_loss_kernel(
        const float* __restrict__ y, const float* __restrict__ g,
        float* __restrict__ acc, int* __restrict__ ticket,
        float* __restrict__ out, int T, int n_frames, float inv_count) {
    __shared__ float2 xch_all[4][512];   // XOR-swizzled transpose scratch (per wave)
    __shared__ float2 tw2_tab[7][8];     // W64^{(lane&7)*k}, k=1..7 (broadcast reads)
    __shared__ float wsum[3][4];
    __shared__ int is_last;

    const int tid  = threadIdx.x;
    const int lane = tid & 63;
    const int wid  = tid >> 6;
    const int l8   = lane & 7;
    float2* xch = xch_all[wid];

    // tw2 table once per block (same __sincosf expressions -> bit-identical).
    if (tid < 56) {
        const int k = (tid >> 3) + 1, l = tid & 7;
        float s, c;
        __sincosf(-(2.0f * PI_F / 64.0f) * (float)(l * k), &s, &c);
        tw2_tab[tid >> 3][l] = make_float2(c, s);
    }
    __syncthreads();

    // Stage-1 twiddles in registers (14 VGPRs), once per kernel.
    cpx tw1[7];
    #pragma unroll
    for (int k = 1; k < 8; ++k) {
        float a1 = -(2.0f * PI_F / 512.0f) * (float)(lane * k);
        __sincosf(a1, &tw1[k - 1].y, &tw1[k - 1].x);
    }

    float ip = 0.f, gd = 0.f, iaf = 0.f;
    cpx Cp[5];
    const int tmax_int = (T - 256) / HOP;   // frames [2, tmax_int] need no reflect
    const int ra1 = (lane >> 3) * 72 + (lane & 7);       // stage-1 read base, XOR (r<<3)
    const int ra2 = (lane >> 3) * 65 + (lane & 7) * 8;   // stage-2 read base, XOR r
    const int rsl = (lane + 63) & 63;                    // rotate-down-1 shuffle source
    const int rsh = (64 - lane) & 63;                    // Hermitian partner source lane

    // Load frame t's 16 samples into vv (reflect-safe for all valid t).
    auto load_frame = [&](int t, cpx* vv) {
        const int base = t * HOP - 256 + lane;
        if (t >= 2 && t <= tmax_int) {       // fast path: no reflect clamps
            #pragma unroll
            for (int r = 0; r < 8; ++r) {
                int j = base + r * 64;
                vv[r].x = y[j]; vv[r].y = g[j];
            }
        } else {
            #pragma unroll
            for (int r = 0; r < 8; ++r) {
                int j = base + r * 64;
                j = (j < 0) ? -j : j;
                j = (j >= T) ? (2 * T - 2 - j) : j;
                vv[r].x = y[j]; vv[r].y = g[j];
            }
        }
    };

    // Compute one frame from preloaded samples (no global loads inside the
    // fence region -> next frame's prefetched loads fly under this compute).
    auto process = [&](cpx* v, bool accum, bool hp) {
        // stage 1: DFT8 over n2, twiddle W512^{lane*k} (registers)
        dft8(v);
        #pragma unroll
        for (int k = 1; k < 8; ++k) v[k] = cmul(v[k], tw1[k - 1]);
        LDS_FENCE();   // orders prev frame's stage-2 reads vs these writes
        #pragma unroll
        for (int k = 0; k < 8; ++k)
            xch[lane ^ (72 * k)] = make_float2(v[k].x, v[k].y);
        LDS_FENCE();
        #pragma unroll
        for (int r = 0; r < 8; ++r) {
            float2 tmp = xch[ra1 ^ (r << 3)];
            v[r] = cpx{tmp.x, tmp.y};
        }
        // stage 2: DFT8, twiddle W64^{(lane&7)*k} from LDS table (broadcast)
        dft8(v);
        #pragma unroll
        for (int k = 1; k < 8; ++k) {
            float2 tw = tw2_tab[k - 1][l8];
            v[k] = cmul(v[k], cpx{tw.x, tw.y});
        }
        LDS_FENCE();
        #pragma unroll
        for (int k = 0; k < 8; ++k)
            xch[lane ^ (65 * k)] = make_float2(v[k].x, v[k].y);
        LDS_FENCE();
        #pragma unroll
        for (int r = 0; r < 8; ++r) {
            float2 tmp = xch[ra2 ^ r];
            v[r] = cpx{tmp.x, tmp.y};
        }
        // stage 3: DFT8 -> bin f = lane + 64*reg, full spectrum in regs
        dft8(v);
        // Hermitian partner via shuffle: lane>=1: v[7-jj] from lane 64-lane;
        // lane==0: own v[(8-jj)&7] (static index).
        cpx Cc[5];
        #pragma unroll
        for (int jj = 0; jj < 5; ++jj) {
            float px = __shfl(v[7 - jj].x, rsh, 64);
            float py = __shfl(v[7 - jj].y, rsh, 64);
            px = (lane == 0) ? v[(8 - jj) & 7].x : px;
            py = (lane == 0) ? v[(8 - jj) & 7].y : py;
            float ur = v[jj].x + px, ui = v[jj].y - py;   // 2*Y
            float vx = v[jj].x - px, vy = v[jj].y + py;   // 2i*G
            Cc[jj].x = fmaf(ur, vy, -ui * vx);            // C = Y*conj(G), x4
            Cc[jj].y = fmaf(ur, vx,  ui * vy);
        }
        if (accum) {
            // C[f-1] via lane-rotate shuffle; lane0 patched from previous jj.
            cpx rprev = {0.f, 0.f};
            #pragma unroll
            for (int jj = 0; jj < 4; ++jj) {
                cpx rj;
                rj.x = __shfl(Cc[jj].x, rsl, 64);
                rj.y = __shfl(Cc[jj].y, rsl, 64);
                cpx cmj = (jj > 0 && lane == 0) ? rprev : rj;
                cpx cc = Cc[jj];
                float aw = abs_angle(cc.x, cc.y);
                ip += aw;
                cpx qg = cmulc(cmj, cc);
                float gt = abs_angle(qg.x, qg.y);
                gd += (jj == 0 && lane == 0) ? aw : gt;   // gd row 0 term == ip term
                if (hp) {
                    cpx qi = cmulc(Cp[jj], cc);
                    iaf += abs_angle(qi.x, qi.y);
                } else {
                    iaf += aw;                             // iaf col 0 term == ip term
                }
                rprev = rj;
            }
            if (lane == 0) {   // bin 256
                cpx cc = Cc[4];
                float aw = abs_angle(cc.x, cc.y);
                ip += aw;
                cpx qg = cmulc(rprev, cc);                // rprev = C[255] at lane 0
                gd += abs_angle(qg.x, qg.y);
                if (hp) {
                    cpx qi = cmulc(Cp[4], cc);
                    iaf += abs_angle(qi.x, qi.y);
                } else {
                    iaf += aw;
                }
            }
        }
        #pragma unroll
        for (int jj = 0; jj < 5; ++jj) Cp[jj] = Cc[jj];
    };

    const int chain   = (blockIdx.x << 2) | wid;        // 0 .. 4*gridDim.x-1
    const int nchains = (int)(gridDim.x << 2);
    const int t0 = chain * FPW;
    int tend = t0 + FPW;
    if (chain == nchains - 1) tend = n_frames;          // last chain takes remainder
    const bool havep = (t0 > 0);

    cpx v[8];
    if (havep) {
        cpx vp[8];
        load_frame(t0 - 1, vp);
        load_frame(t0, v);          // prefetch: first real frame's loads hide
        process(vp, false, false);  //   under the prologue compute
    } else {
        load_frame(t0, v);
    }
    #pragma unroll 2
    for (int t = t0; t < tend; ++t) {
        cpx vn[8];
        const bool pf = (t + 1 < tend);
        if (pf) load_frame(t + 1, vn);   // issue t+1's loads BEFORE t's fences
        process(v, true, havep || (t > t0));
        if (pf) {
            #pragma unroll
            for (int r = 0; r < 8; ++r) v[r] = vn[r];
        }
    }

    // block reduce
    __syncthreads();
    for (int off = 32; off; off >>= 1) {
        ip  += __shfl_down(ip, off);
        gd  += __shfl_down(gd, off);
        iaf += __shfl_down(iaf, off);
    }
    if (lane == 0) { wsum[0][wid] = ip; wsum[1][wid] = gd; wsum[2][wid] = iaf; }
    __syncthreads();
    if (tid == 0) {
        const int slot = (int)(blockIdx.x & (NSLOTS - 1));
        atomicAdd(acc + 0 * NSLOTS + slot, wsum[0][0] + wsum[0][1] + wsum[0][2] + wsum[0][3]);
        atomicAdd(acc + 1 * NSLOTS + slot, wsum[1][0] + wsum[1][1] + wsum[1][2] + wsum[1][3]);
        atomicAdd(acc + 2 * NSLOTS + slot, wsum[2][0] + wsum[2][1] + wsum[2][2] + wsum[2][3]);
        __threadfence();
        is_last = (atomicAdd(ticket, 1) == (int)gridDim.x - 1);
    }
    __syncthreads();
    if (is_last) {
        for (int l = 0; l < 3; l++) {
            float vv = __hip_atomic_load(acc + l * NSLOTS + tid,
                                         __ATOMIC_RELAXED, __HIP_MEMORY_SCOPE_AGENT);
            for (int off = 32; off; off >>= 1) vv += __shfl_down(vv, off);
            if (lane == 0) wsum[l][wid] = vv;
        }
        __syncthreads();
        if (tid < 3)
            out[tid] = (wsum[tid][0] + wsum[tid][1] + wsum[tid][2] + wsum[tid][3]) * inv_count;
    }
}

extern "C" void kernel_launch(void* const* d_in, const int* in_sizes, int n_in,
                              void* d_out, int out_size, void* d_ws, size_t ws_size,
                              hipStream_t stream) {
    const float* y = (const float*)d_in[0];
    const float* g = (const float*)d_in[1];
    float* out = (float*)d_out;
    float* acc = (float*)d_ws;
    int* ticket = (int*)((char*)d_ws + 3 * NSLOTS * sizeof(float));
    const int T = in_sizes[0];
    const int n_frames = T / HOP + 1;                  // 32769
    int n_blocks = n_frames / (FPW * 4);               // 1024 (last chain absorbs rest)
    if (n_blocks < 1) n_blocks = 1;

    hipMemsetAsync(d_ws, 0, 3 * NSLOTS * sizeof(float) + sizeof(int), stream);
    const float inv_count = 1.0f / (257.0f * (float)n_frames);
    phase_loss_kernel<<<n_blocks, 256, 0, stream>>>(y, g, acc, ticket, out,
                                                    T, n_frames, inv_count);
}

// Round 9
// 133.491 us; speedup vs baseline: 2.0710x; 1.0186x over previous
//
#include <hip/hip_runtime.h>
#include <math.h>

#define HOP     128
#define NSLOTS  256
#define FPW     8      // frames per chain; 2 chains per wave (ILP) -> 512 blocks
#define PI_F    3.14159265358979323846f
#define PI2_F   1.57079632679489661923f
#define K8      0.70710678118654752440f

// Zero-instruction ordering fence for intra-wave LDS cross-lane handoffs.
#define LDS_FENCE() do { __asm__ volatile("" ::: "memory"); \
                         __builtin_amdgcn_wave_barrier(); } while (0)

struct cpx { float x, y; };
__device__ __forceinline__ cpx cadd(cpx a, cpx b){ return {a.x+b.x, a.y+b.y}; }
__device__ __forceinline__ cpx csub(cpx a, cpx b){ return {a.x-b.x, a.y-b.y}; }
__device__ __forceinline__ cpx cmul(cpx a, cpx b){
    return {fmaf(a.x,b.x,-a.y*b.y), fmaf(a.x,b.y, a.y*b.x)};
}
__device__ __forceinline__ cpx cmulc(cpx a, cpx b){  // a*conj(b)
    return {fmaf(a.x,b.x, a.y*b.y), fmaf(a.y,b.x,-a.x*b.y)};
}

// |atan2(im,re)| in [0,pi]
__device__ __forceinline__ float abs_angle(float re, float im) {
    float a = fabsf(im), b = fabsf(re);
    float mn = fminf(a, b), mx = fmaxf(a, b);
    float t = __fdividef(mn, fmaxf(mx, 1e-37f));
    float t2 = t * t;
    float p = fmaf(t2, -0.0117212f, 0.05265332f);
    p = fmaf(t2, p, -0.11643287f);
    p = fmaf(t2, p, 0.19354346f);
    p = fmaf(t2, p, -0.33262347f);
    p = fmaf(t2, p, 0.99997726f);
    float r = t * p;
    r = (a > b) ? (PI2_F - r) : r;
    r = (re < 0.f) ? (PI_F - r) : r;
    return r;
}

// In-register 8-point DFT, natural-order output.
__device__ __forceinline__ void dft8(cpx v[8]) {
    cpx a0=cadd(v[0],v[4]), a1=cadd(v[1],v[5]), a2=cadd(v[2],v[6]), a3=cadd(v[3],v[7]);
    cpx b0=csub(v[0],v[4]), b1=csub(v[1],v[5]), b2=csub(v[2],v[6]), b3=csub(v[3],v[7]);
    b1 = cpx{K8*(b1.x+b1.y), K8*(b1.y-b1.x)};   // * e^{-i pi/4}
    b2 = cpx{b2.y, -b2.x};                      // * -i
    b3 = cpx{K8*(b3.y-b3.x), -K8*(b3.x+b3.y)};  // * e^{-3i pi/4}
    cpx c0=cadd(a0,a2), c2=csub(a0,a2);
    cpx c1=cadd(a1,a3), c3=csub(a1,a3); c3 = cpx{c3.y, -c3.x};
    cpx d0=cadd(b0,b2), d2=csub(b0,b2);
    cpx d1=cadd(b1,b3), d3=csub(b1,b3); d3 = cpx{d3.y, -d3.x};
    v[0]=cadd(c0,c1); v[4]=csub(c0,c1);
    v[2]=cadd(c2,c3); v[6]=csub(c2,c3);
    v[1]=cadd(d0,d1); v[5]=csub(d0,d1);
    v[3]=cadd(d2,d3); v[7]=csub(d2,d3);
}

// Dual-stream ILP: each wave runs TWO adjacent chains (A,B) in lockstep.
// Every stall point (fence lgkmcnt waits, shuffle waits, load waits) now has
// an independent second instruction stream inside the same wave — issue
// density no longer depends on the SIMD scheduler finding another warm wave.
// Grid only needs 8 waves/CU, so launch_bounds(256,2) leaves the allocator
// ample headroom (r1 lesson: never squeeze it).
__global__ __launch_bounds__(256, 2) void phase_loss_kernel(
        const float* __restrict__ y, const float* __restrict__ g,
        float* __restrict__ acc, int* __restrict__ ticket,
        float* __restrict__ out, int T, int n_frames, float inv_count) {
    __shared__ float2 xch_all[4][2][512];  // per wave, per stream, XOR-swizzled
    __shared__ float2 tw2_tab[7][8];       // W64^{(lane&7)*k}, shared by streams
    __shared__ float wsum[3][4];
    __shared__ int is_last;

    const int tid  = threadIdx.x;
    const int lane = tid & 63;
    const int wid  = tid >> 6;
    const int l8   = lane & 7;
    float2* xcha = xch_all[wid][0];
    float2* xchb = xch_all[wid][1];

    // tw2 table once per block (same __sincosf expressions -> bit-identical).
    if (tid < 56) {
        const int k = (tid >> 3) + 1, l = tid & 7;
        float s, c;
        __sincosf(-(2.0f * PI_F / 64.0f) * (float)(l * k), &s, &c);
        tw2_tab[tid >> 3][l] = make_float2(c, s);
    }
    __syncthreads();

    // Stage-1 twiddles in registers (14 VGPRs), shared by both streams.
    cpx tw1[7];
    #pragma unroll
    for (int k = 1; k < 8; ++k) {
        float a1 = -(2.0f * PI_F / 512.0f) * (float)(lane * k);
        __sincosf(a1, &tw1[k - 1].y, &tw1[k - 1].x);
    }

    float ipA = 0.f, gdA = 0.f, iafA = 0.f;
    float ipB = 0.f, gdB = 0.f, iafB = 0.f;
    cpx CpA[5], CpB[5];
    #pragma unroll
    for (int jj = 0; jj < 5; ++jj) { CpA[jj] = cpx{0.f,0.f}; CpB[jj] = cpx{0.f,0.f}; }

    const int tmax_int = (T - 256) / HOP;   // frames [2, tmax_int] need no reflect
    const int ra1 = (lane >> 3) * 72 + (lane & 7);       // stage-1 read base, XOR (r<<3)
    const int ra2 = (lane >> 3) * 65 + (lane & 7) * 8;   // stage-2 read base, XOR r
    const int rsl = (lane + 63) & 63;                    // rotate-down-1 shuffle source
    const int rsh = (64 - lane) & 63;                    // Hermitian partner source lane

    auto load_frame = [&](int t, cpx* vv) {
        const int base = t * HOP - 256 + lane;
        if (t >= 2 && t <= tmax_int) {       // fast path: no reflect clamps
            #pragma unroll
            for (int r = 0; r < 8; ++r) {
                int j = base + r * 64;
                vv[r].x = y[j]; vv[r].y = g[j];
            }
        } else {
            #pragma unroll
            for (int r = 0; r < 8; ++r) {
                int j = base + r * 64;
                j = (j < 0) ? -j : j;
                j = (j >= T) ? (2 * T - 2 - j) : j;
                vv[r].x = y[j]; vv[r].y = g[j];
            }
        }
    };

    // Hermitian split: lane>=1: partner = v[7-jj] from lane 64-lane;
    // lane==0: own v[(8-jj)&7] (static index). C = Y*conj(G), x4.
    auto herm_C = [&](cpx* v, cpx* Cc) {
        #pragma unroll
        for (int jj = 0; jj < 5; ++jj) {
            float px = __shfl(v[7 - jj].x, rsh, 64);
            float py = __shfl(v[7 - jj].y, rsh, 64);
            px = (lane == 0) ? v[(8 - jj) & 7].x : px;
            py = (lane == 0) ? v[(8 - jj) & 7].y : py;
            float ur = v[jj].x + px, ui = v[jj].y - py;   // 2*Y
            float vx = v[jj].x - px, vy = v[jj].y + py;   // 2i*G
            Cc[jj].x = fmaf(ur, vy, -ui * vx);
            Cc[jj].y = fmaf(ur, vx,  ui * vy);
        }
    };

    auto accum_frame = [&](cpx* Cc, cpx* Cp, float& ip, float& gd, float& iaf,
                           bool hp) {
        // C[f-1] via lane-rotate shuffle; lane0 patched from previous jj.
        cpx rprev = {0.f, 0.f};
        #pragma unroll
        for (int jj = 0; jj < 4; ++jj) {
            cpx rj;
            rj.x = __shfl(Cc[jj].x, rsl, 64);
            rj.y = __shfl(Cc[jj].y, rsl, 64);
            cpx cmj = (jj > 0 && lane == 0) ? rprev : rj;
            cpx cc = Cc[jj];
            float aw = abs_angle(cc.x, cc.y);
            ip += aw;
            cpx qg = cmulc(cmj, cc);
            float gt = abs_angle(qg.x, qg.y);
            gd += (jj == 0 && lane == 0) ? aw : gt;   // gd row 0 term == ip term
            if (hp) {
                cpx qi = cmulc(Cp[jj], cc);
                iaf += abs_angle(qi.x, qi.y);
            } else {
                iaf += aw;                             // iaf col 0 term == ip term
            }
            rprev = rj;
        }
        if (lane == 0) {   // bin 256
            cpx cc = Cc[4];
            float aw = abs_angle(cc.x, cc.y);
            ip += aw;
            cpx qg = cmulc(rprev, cc);                // rprev = C[255] at lane 0
            gd += abs_angle(qg.x, qg.y);
            if (hp) {
                cpx qi = cmulc(Cp[4], cc);
                iaf += abs_angle(qi.x, qi.y);
            } else {
                iaf += aw;
            }
        }
    };

    // Both streams advance through the same fence windows: their LDS ops share
    // one lgkmcnt wait, their VALU interleaves freely inside each window.
    auto process2 = [&](int tA, int tB, bool doA, bool doB, bool acc2,
                        bool hpA, bool hpB) {
        cpx va[8] = {}, vb[8] = {};
        if (doA) load_frame(tA, va);
        if (doB) load_frame(tB, vb);
        // stage 1
        dft8(va); dft8(vb);
        #pragma unroll
        for (int k = 1; k < 8; ++k) {
            va[k] = cmul(va[k], tw1[k - 1]);
            vb[k] = cmul(vb[k], tw1[k - 1]);
        }
        LDS_FENCE();
        #pragma unroll
        for (int k = 0; k < 8; ++k) {
            xcha[lane ^ (72 * k)] = make_float2(va[k].x, va[k].y);
            xchb[lane ^ (72 * k)] = make_float2(vb[k].x, vb[k].y);
        }
        LDS_FENCE();
        #pragma unroll
        for (int r = 0; r < 8; ++r) {
            float2 ta = xcha[ra1 ^ (r << 3)];
            float2 tb = xchb[ra1 ^ (r << 3)];
            va[r] = cpx{ta.x, ta.y}; vb[r] = cpx{tb.x, tb.y};
        }
        // stage 2
        dft8(va); dft8(vb);
        #pragma unroll
        for (int k = 1; k < 8; ++k) {
            float2 tw = tw2_tab[k - 1][l8];              // read once, use twice
            va[k] = cmul(va[k], cpx{tw.x, tw.y});
            vb[k] = cmul(vb[k], cpx{tw.x, tw.y});
        }
        LDS_FENCE();
        #pragma unroll
        for (int k = 0; k < 8; ++k) {
            xcha[lane ^ (65 * k)] = make_float2(va[k].x, va[k].y);
            xchb[lane ^ (65 * k)] = make_float2(vb[k].x, vb[k].y);
        }
        LDS_FENCE();
        #pragma unroll
        for (int r = 0; r < 8; ++r) {
            float2 ta = xcha[ra2 ^ r];
            float2 tb = xchb[ra2 ^ r];
            va[r] = cpx{ta.x, ta.y}; vb[r] = cpx{tb.x, tb.y};
        }
        // stage 3
        dft8(va); dft8(vb);
        cpx CcA[5], CcB[5];
        herm_C(va, CcA);
        herm_C(vb, CcB);
        if (acc2) {
            if (doA) accum_frame(CcA, CpA, ipA, gdA, iafA, hpA);
            if (doB) accum_frame(CcB, CpB, ipB, gdB, iafB, hpB);
        }
        if (doA) {
            #pragma unroll
            for (int jj = 0; jj < 5; ++jj) CpA[jj] = CcA[jj];
        }
        if (doB) {
            #pragma unroll
            for (int jj = 0; jj < 5; ++jj) CpB[jj] = CcB[jj];
        }
    };

    const int wch     = (blockIdx.x << 2) | wid;        // 0 .. 4*gridDim.x-1
    const int nchains = (int)(gridDim.x << 3);          // 2 chains per wave
    const int cA = wch * 2, cB = wch * 2 + 1;
    const int t0A = cA * FPW, t0B = cB * FPW;
    int tendB = t0B + FPW;
    if (cB == nchains - 1) tendB = n_frames;            // last chain takes remainder
    const bool havepA = (t0A > 0);

    // prologue frames (accum=false) — fills CpA/CpB
    process2(t0A - 1, t0B - 1, havepA, true, false, false, false);
    #pragma unroll 1
    for (int t = 0; t < FPW; ++t)
        process2(t0A + t, t0B + t, true, true, true, havepA || (t > 0), true);
    #pragma unroll 1
    for (int t = FPW; t < tendB - t0B; ++t)             // last wave's B-tail only
        process2(0, t0B + t, false, true, true, false, true);

    float ip = ipA + ipB, gd = gdA + gdB, iaf = iafA + iafB;

    // block reduce
    __syncthreads();
    for (int off = 32; off; off >>= 1) {
        ip  += __shfl_down(ip, off);
        gd  += __shfl_down(gd, off);
        iaf += __shfl_down(iaf, off);
    }
    if (lane == 0) { wsum[0][wid] = ip; wsum[1][wid] = gd; wsum[2][wid] = iaf; }
    __syncthreads();
    if (tid == 0) {
        const int slot = (int)(blockIdx.x & (NSLOTS - 1));
        atomicAdd(acc + 0 * NSLOTS + slot, wsum[0][0] + wsum[0][1] + wsum[0][2] + wsum[0][3]);
        atomicAdd(acc + 1 * NSLOTS + slot, wsum[1][0] + wsum[1][1] + wsum[1][2] + wsum[1][3]);
        atomicAdd(acc + 2 * NSLOTS + slot, wsum[2][0] + wsum[2][1] + wsum[2][2] + wsum[2][3]);
        __threadfence();
        is_last = (atomicAdd(ticket, 1) == (int)gridDim.x - 1);
    }
    __syncthreads();
    if (is_last) {
        for (int l = 0; l < 3; l++) {
            float vv = __hip_atomic_load(acc + l * NSLOTS + tid,
                                         __ATOMIC_RELAXED, __HIP_MEMORY_SCOPE_AGENT);
            for (int off = 32; off; off >>= 1) vv += __shfl_down(vv, off);
            if (lane == 0) wsum[l][wid] = vv;
        }
        __syncthreads();
        if (tid < 3)
            out[tid] = (wsum[tid][0] + wsum[tid][1] + wsum[tid][2] + wsum[tid][3]) * inv_count;
    }
}

extern "C" void kernel_launch(void* const* d_in, const int* in_sizes, int n_in,
                              void* d_out, int out_size, void* d_ws, size_t ws_size,
                              hipStream_t stream) {
    const float* y = (const float*)d_in[0];
    const float* g = (const float*)d_in[1];
    float* out = (float*)d_out;
    float* acc = (float*)d_ws;
    int* ticket = (int*)((char*)d_ws + 3 * NSLOTS * sizeof(float));
    const int T = in_sizes[0];
    const int n_frames = T / HOP + 1;                  // 32769
    int n_blocks = n_frames / (FPW * 8);               // 512 (last chain absorbs rest)
    if (n_blocks < 1) n_blocks = 1;

    hipMemsetAsync(d_ws, 0, 3 * NSLOTS * sizeof(float) + sizeof(int), stream);
    const float inv_count = 1.0f / (257.0f * (float)n_frames);
    phase_loss_kernel<<<n_blocks, 256, 0, stream>>>(y, g, acc, ticket, out,
                                                    T, n_frames, inv_count);
}